// Round 1
// baseline (10318.292 us; speedup 1.0000x reference)
//
#include <hip/hip_runtime.h>

// MEGConv: NA=NB=2e6, NG=2e5, D=32.
// d_out layout: atom_new[NA*32] | bond_new[NB*32] | glob_new[NG*32]  (fp32)
// Scratch: bond_sum[NA*32] lives in d_out's bond region (NB>=NA here, consumed
// before bond_new is written). d_ws holds: bcnt[NA] | asumg[NG*32] | acntg[NG]
// | bsumg[NG*32] | bcntg[NG]  (~61 MB).

#define TPB 256

__global__ void zero4_kernel(float4* __restrict__ p, long n4) {
  long i = (long)blockIdx.x * blockDim.x + threadIdx.x;
  long stride = (long)gridDim.x * blockDim.x;
  float4 z = make_float4(0.f, 0.f, 0.f, 0.f);
  for (; i < n4; i += stride) p[i] = z;
}

// One thread per (bond, dim): scatter bond feats to both endpoint atoms.
__global__ void scatter_bonds_kernel(const float* __restrict__ bf,
                                     const int* __restrict__ ba,
                                     float* __restrict__ bsum,
                                     float* __restrict__ bcnt, int NB) {
  int gid = blockIdx.x * blockDim.x + threadIdx.x;
  int b = gid >> 5;
  if (b >= NB) return;
  int d = gid & 31;
  int a0 = ba[2 * b];
  int a1 = ba[2 * b + 1];
  float v = bf[(long)b * 32 + d];
  atomicAdd(&bsum[(long)a0 * 32 + d], v);
  atomicAdd(&bsum[(long)a1 * 32 + d], v);
  if (d == 0) {
    atomicAdd(&bcnt[a0], 1.f);
    atomicAdd(&bcnt[a1], 1.f);
  }
}

__device__ __forceinline__ float softplus_f(float v) {
  // log1p(exp(v)), numerically stable
  return fmaxf(v, 0.f) + log1pf(expf(-fabsf(v)));
}

// Accumulate one 32-wide input chunk into h1[64]: h1 += (x*scale) @ W[32,64].
// Wrow is wave-uniform -> scalar loads; xrow is lane-varying.
__device__ __forceinline__ void l1_chunk(float h1[64],
                                         const float* __restrict__ xrow,
                                         float scale,
                                         const float* __restrict__ Wrow) {
  #pragma unroll 4
  for (int k = 0; k < 32; ++k) {
    float xv = xrow[k] * scale;
    #pragma unroll
    for (int j = 0; j < 64; ++j) h1[j] = fmaf(xv, Wrow[k * 64 + j], h1[j]);
  }
}

// softplus(h1) -> h2 = softplus(h1@W2+b2) -> o = h2@W3+b3
__device__ __forceinline__ void mlp_tail(float h1[64],
                                         const float* __restrict__ W2,
                                         const float* __restrict__ B2,
                                         const float* __restrict__ W3,
                                         const float* __restrict__ B3,
                                         float o[32]) {
  #pragma unroll
  for (int j = 0; j < 64; ++j) h1[j] = softplus_f(h1[j]);
  float h2[64];
  #pragma unroll
  for (int j = 0; j < 64; ++j) h2[j] = B2[j];
  #pragma unroll
  for (int k = 0; k < 64; ++k) {
    float xv = h1[k];
    #pragma unroll
    for (int j = 0; j < 64; ++j) h2[j] = fmaf(xv, W2[k * 64 + j], h2[j]);
  }
  #pragma unroll
  for (int j = 0; j < 64; ++j) h2[j] = softplus_f(h2[j]);
  #pragma unroll
  for (int j = 0; j < 32; ++j) o[j] = B3[j];
  #pragma unroll
  for (int k = 0; k < 64; ++k) {
    float xv = h2[k];
    #pragma unroll
    for (int j = 0; j < 32; ++j) o[j] = fmaf(xv, W3[k * 32 + j], o[j]);
  }
}

__global__ void __launch_bounds__(TPB)
atom_mlp_kernel(const float* __restrict__ af, const float* __restrict__ bsum,
                const float* __restrict__ bcnt, const float* __restrict__ gf,
                const int* __restrict__ amol,
                const float* __restrict__ W1, const float* __restrict__ B1,
                const float* __restrict__ W2, const float* __restrict__ B2,
                const float* __restrict__ W3, const float* __restrict__ B3,
                float* __restrict__ out_atom, float* __restrict__ gsum,
                float* __restrict__ gcnt, int NA) {
  int a = blockIdx.x * TPB + threadIdx.x;
  if (a >= NA) return;
  float h1[64];
  #pragma unroll
  for (int j = 0; j < 64; ++j) h1[j] = B1[j];
  l1_chunk(h1, af + (long)a * 32, 1.f, W1);
  float c = bcnt[a];
  float inv = c > 0.f ? 1.f / c : 0.f;
  l1_chunk(h1, bsum + (long)a * 32, inv, W1 + 32 * 64);
  int g = amol[a];
  l1_chunk(h1, gf + (long)g * 32, 1.f, W1 + 64 * 64);
  float o[32];
  mlp_tail(h1, W2, B2, W3, B3, o);
  float4* dst = (float4*)(out_atom + (long)a * 32);
  #pragma unroll
  for (int q = 0; q < 8; ++q)
    dst[q] = make_float4(o[4 * q], o[4 * q + 1], o[4 * q + 2], o[4 * q + 3]);
  #pragma unroll
  for (int d = 0; d < 32; ++d) atomicAdd(&gsum[(long)g * 32 + d], o[d]);
  atomicAdd(&gcnt[g], 1.f);
}

__global__ void __launch_bounds__(TPB)
bond_mlp_kernel(const float* __restrict__ bf, const float* __restrict__ atom_new,
                const float* __restrict__ gf, const int* __restrict__ ba,
                const int* __restrict__ bmol,
                const float* __restrict__ W1, const float* __restrict__ B1,
                const float* __restrict__ W2, const float* __restrict__ B2,
                const float* __restrict__ W3, const float* __restrict__ B3,
                float* __restrict__ out_bond, float* __restrict__ gsum,
                float* __restrict__ gcnt, int NB) {
  int b = blockIdx.x * TPB + threadIdx.x;
  if (b >= NB) return;
  float h1[64];
  #pragma unroll
  for (int j = 0; j < 64; ++j) h1[j] = B1[j];
  l1_chunk(h1, bf + (long)b * 32, 1.f, W1);
  int a0 = ba[2 * b];
  int a1 = ba[2 * b + 1];
  l1_chunk(h1, atom_new + (long)a0 * 32, 1.f, W1 + 32 * 64);
  l1_chunk(h1, atom_new + (long)a1 * 32, 1.f, W1 + 64 * 64);
  int g = bmol[b];
  l1_chunk(h1, gf + (long)g * 32, 1.f, W1 + 96 * 64);
  float o[32];
  mlp_tail(h1, W2, B2, W3, B3, o);
  float4* dst = (float4*)(out_bond + (long)b * 32);
  #pragma unroll
  for (int q = 0; q < 8; ++q)
    dst[q] = make_float4(o[4 * q], o[4 * q + 1], o[4 * q + 2], o[4 * q + 3]);
  #pragma unroll
  for (int d = 0; d < 32; ++d) atomicAdd(&gsum[(long)g * 32 + d], o[d]);
  atomicAdd(&gcnt[g], 1.f);
}

__global__ void __launch_bounds__(TPB)
glob_mlp_kernel(const float* __restrict__ gf, const float* __restrict__ asum,
                const float* __restrict__ acnt, const float* __restrict__ bsum,
                const float* __restrict__ bcnt,
                const float* __restrict__ W1, const float* __restrict__ B1,
                const float* __restrict__ W2, const float* __restrict__ B2,
                const float* __restrict__ W3, const float* __restrict__ B3,
                float* __restrict__ out_glob, int NG) {
  int m = blockIdx.x * TPB + threadIdx.x;
  if (m >= NG) return;
  float h1[64];
  #pragma unroll
  for (int j = 0; j < 64; ++j) h1[j] = B1[j];
  l1_chunk(h1, gf + (long)m * 32, 1.f, W1);
  float ca = acnt[m];
  float inva = ca > 0.f ? 1.f / ca : 0.f;
  l1_chunk(h1, asum + (long)m * 32, inva, W1 + 32 * 64);
  float cb = bcnt[m];
  float invb = cb > 0.f ? 1.f / cb : 0.f;
  l1_chunk(h1, bsum + (long)m * 32, invb, W1 + 64 * 64);
  float o[32];
  mlp_tail(h1, W2, B2, W3, B3, o);
  float4* dst = (float4*)(out_glob + (long)m * 32);
  #pragma unroll
  for (int q = 0; q < 8; ++q)
    dst[q] = make_float4(o[4 * q], o[4 * q + 1], o[4 * q + 2], o[4 * q + 3]);
}

extern "C" void kernel_launch(void* const* d_in, const int* in_sizes, int n_in,
                              void* d_out, int out_size, void* d_ws, size_t ws_size,
                              hipStream_t stream) {
  const float* af = (const float*)d_in[0];
  const float* bf = (const float*)d_in[1];
  const float* gf = (const float*)d_in[2];
  const int* ba = (const int*)d_in[3];
  const int* amol = (const int*)d_in[4];
  const int* bmol = (const int*)d_in[5];
  const float* aW1 = (const float*)d_in[6];
  const float* ab1 = (const float*)d_in[7];
  const float* aW2 = (const float*)d_in[8];
  const float* ab2 = (const float*)d_in[9];
  const float* aW3 = (const float*)d_in[10];
  const float* ab3 = (const float*)d_in[11];
  const float* bW1 = (const float*)d_in[12];
  const float* bb1 = (const float*)d_in[13];
  const float* bW2 = (const float*)d_in[14];
  const float* bb2 = (const float*)d_in[15];
  const float* bW3 = (const float*)d_in[16];
  const float* bb3 = (const float*)d_in[17];
  const float* gW1 = (const float*)d_in[18];
  const float* gb1 = (const float*)d_in[19];
  const float* gW2 = (const float*)d_in[20];
  const float* gb2 = (const float*)d_in[21];
  const float* gW3 = (const float*)d_in[22];
  const float* gb3 = (const float*)d_in[23];

  const int NA = in_sizes[0] / 32;
  const int NB = in_sizes[1] / 32;
  const int NG = in_sizes[2] / 32;

  float* out = (float*)d_out;
  float* out_atom = out;
  float* out_bond = out + (long)NA * 32;
  float* out_glob = out + (long)NA * 32 + (long)NB * 32;

  // bond_sum scratch reuses the bond_new output region (NB*32 >= NA*32 here;
  // consumed by atom_mlp before bond_mlp overwrites it with bond_new).
  float* bsum = out_bond;
  float* ws = (float*)d_ws;
  float* bcnt = ws;                        // [NA]
  float* asumg = bcnt + (long)NA;          // [NG*32]
  float* acntg = asumg + (long)NG * 32;    // [NG]
  float* bsumg = acntg + (long)NG;         // [NG*32]
  // bcntg = bsumg + NG*32                 // [NG]
  float* bcntg = bsumg + (long)NG * 32;

  long z1 = ((long)NA * 32) / 4;                 // bond_sum floats /4
  long z2 = ((long)NA + (long)NG * 66 + 3) / 4;  // ws floats /4
  zero4_kernel<<<dim3(2048), dim3(TPB), 0, stream>>>((float4*)bsum, z1);
  zero4_kernel<<<dim3(2048), dim3(TPB), 0, stream>>>((float4*)ws, z2);

  long nscatter = (long)NB * 32;
  scatter_bonds_kernel<<<dim3((nscatter + TPB - 1) / TPB), dim3(TPB), 0, stream>>>(
      bf, ba, bsum, bcnt, NB);

  atom_mlp_kernel<<<dim3((NA + TPB - 1) / TPB), dim3(TPB), 0, stream>>>(
      af, bsum, bcnt, gf, amol, aW1, ab1, aW2, ab2, aW3, ab3, out_atom, asumg,
      acntg, NA);

  bond_mlp_kernel<<<dim3((NB + TPB - 1) / TPB), dim3(TPB), 0, stream>>>(
      bf, out_atom, gf, ba, bmol, bW1, bb1, bW2, bb2, bW3, bb3, out_bond, bsumg,
      bcntg, NB);

  glob_mlp_kernel<<<dim3((NG + TPB - 1) / TPB), dim3(TPB), 0, stream>>>(
      gf, asumg, acntg, bsumg, bcntg, gW1, gb1, gW2, gb2, gW3, gb3, out_glob,
      NG);
}